// Round 1
// baseline (26.685 us; speedup 1.0000x reference)
//
#include <hip/hip_runtime.h>
#include <hip/hip_bf16.h>

#define EPSV 1e-6f
#define SIGMA_V 1.0f

// One thread per (n,i) row. 8-lane groups (one n each) share t0/durations via
// shuffles; SatT transpose goes through a small padded LDS tile.
__global__ __launch_bounds__(256) void rank_partial(
    const float* __restrict__ durations,
    const float* __restrict__ survival,
    const float* __restrict__ hazard,
    const float* __restrict__ cuts,
    const int* __restrict__ events,
    float* __restrict__ partials,
    int NE, int K)
{
    __shared__ float s_cuts[256];   // K == 256 for this problem
    __shared__ float s_S[256][9];   // SatT tile, +1 pad: 2-way bank alias only
    __shared__ float s_wsum[4];

    const int tid = threadIdx.x;
    for (int k = tid; k < K; k += 256) s_cuts[k] = cuts[k];
    __syncthreads();

    const int gid = blockIdx.x * 256 + tid;      // = n*8 + i
    const bool valid = gid < NE;
    const float d_i = valid ? durations[gid] : 0.f;
    const int   ev_i = valid ? events[gid] : 0;

    // count = #cuts <= d_i (upper bound over ascending cuts); t0 = count-1
    int lo = 0, hi = K;
    while (lo < hi) { int mid = (lo + hi) >> 1; if (s_cuts[mid] <= d_i) lo = mid + 1; else hi = mid; }
    int t0_i = lo - 1;
    if (t0_i < 0) t0_i = 0;
    if (t0_i > K - 1) t0_i = K - 1;
    const int t1_i = (t0_i + 1 < K) ? t0_i + 1 : K - 1;
    const float T0_i = s_cuts[t0_i];
    const float dT_i = s_cuts[t1_i] - T0_i;

    const float t_end = s_cuts[K - 1];
    const float t_eps = (t_end - s_cuts[0]) / t_end;

    const float* __restrict__ srow = survival + (long long)gid * K;
    const float* __restrict__ hrow = hazard   + (long long)gid * K;

    float SatT_loc[8], SatTM_loc[8];
    const int i = tid & 7;

    #pragma unroll
    for (int j = 0; j < 8; ++j) {
        const float d_j  = __shfl(d_i,  j, 8);
        const int   t0_j = __shfl(t0_i, j, 8);
        const float T0_j = __shfl(T0_i, j, 8);
        const float dT_j = __shfl(dT_i, j, 8);
        float sT = 0.f, sTM = 0.f;
        if (valid) {
            const int t1_j = (t0_j + 1 < K) ? t0_j + 1 : K - 1;
            const float S0 = srow[t0_j];
            const float S1 = srow[t1_j];
            float hstar;
            if (dT_j > 0.f)
                hstar = (__logf(EPSV + S0) - __logf(EPSV + S1)) / dT_j;
            else
                hstar = hrow[t0_j];   // dead for this data; kept for generality
            sT = S0 * __expf(-(d_j - T0_j) * hstar);
            const float tm = fmaxf(d_j - t_eps, 0.f);
            sTM = S0 * __expf(-(tm - T0_j) * hstar);
        }
        SatT_loc[j] = sT;
        SatTM_loc[j] = sTM;
        s_S[tid][j] = sT;
    }
    const float diagS_i  = SatT_loc[i];   // SatT[i][i]
    const float diagSM_i = SatTM_loc[i];  // SatTMinus[i][i]
    __syncthreads();

    const float I_i = (float)ev_i;
    float acc = 0.f;
    const int base = tid & ~7;
    #pragma unroll
    for (int j = 0; j < 8; ++j) {
        const float d_j = __shfl(d_i, j, 8);
        const float I_j = (float)__shfl(ev_i, j, 8);
        const float diagS_j  = __shfl(diagS_i,  j, 8);
        const float diagSM_j = __shfl(diagSM_i, j, 8);
        // A1 = I_i * (d_j > d_i); skip the exps when zero (~75% of pairs)
        if (I_i != 0.f && d_j > d_i) {
            const float sT_ji = s_S[base + j][i];                 // SatT[j][i]
            const float e1 = __expf((diagS_i - sT_ji)      * (1.0f / SIGMA_V));
            const float e2 = __expf((SatTM_loc[j] - diagSM_j) * (1.0f / SIGMA_V));
            const float e3 = __expf((SatT_loc[j]  - diagS_j)  * (1.0f / SIGMA_V));
            acc += e1 + I_j * e2 + (1.f - I_j) * e3;
        }
    }

    // deterministic wave reduce then block partial
    #pragma unroll
    for (int off = 32; off > 0; off >>= 1) acc += __shfl_down(acc, off, 64);
    if ((tid & 63) == 0) s_wsum[tid >> 6] = acc;
    __syncthreads();
    if (tid == 0)
        partials[blockIdx.x] = (s_wsum[0] + s_wsum[1]) + (s_wsum[2] + s_wsum[3]);
}

__global__ __launch_bounds__(256) void rank_finalize(
    const float* __restrict__ partials, int nb,
    const float* __restrict__ weights,
    float* __restrict__ out, float inv_count)
{
    __shared__ float s[256];
    const int tid = threadIdx.x;
    float a = 0.f;
    for (int idx = tid; idx < nb; idx += 256) a += partials[idx];
    s[tid] = a;
    __syncthreads();
    #pragma unroll
    for (int off = 128; off > 0; off >>= 1) {
        if (tid < off) s[tid] += s[tid + off];
        __syncthreads();
    }
    if (tid == 0) out[0] = s[0] * weights[0] * inv_count;
}

extern "C" void kernel_launch(void* const* d_in, const int* in_sizes, int n_in,
                              void* d_out, int out_size, void* d_ws, size_t ws_size,
                              hipStream_t stream) {
    const float* durations = (const float*)d_in[0];
    const float* survival  = (const float*)d_in[1];
    const float* hazard    = (const float*)d_in[2];
    const float* weights   = (const float*)d_in[3];
    const float* cuts      = (const float*)d_in[4];
    const int*   events    = (const int*)d_in[5];

    const int NE = in_sizes[0];       // N * 8
    const int K  = in_sizes[4];       // 256
    const int nb = (NE + 255) / 256;

    float* partials = (float*)d_ws;
    float* out = (float*)d_out;

    rank_partial<<<nb, 256, 0, stream>>>(durations, survival, hazard, cuts,
                                         events, partials, NE, K);

    // mean over n*e*e = NE*8 elements (e = 8)
    const float inv_count = 1.0f / ((float)NE * 8.0f);
    rank_finalize<<<1, 256, 0, stream>>>(partials, nb, weights, out, inv_count);
}